// Round 7
// baseline (201.239 us; speedup 1.0000x reference)
//
#include <hip/hip_runtime.h>
#include <math.h>

#define NN 512

typedef __attribute__((ext_vector_type(8))) short bf16x8;
typedef __attribute__((ext_vector_type(4))) float f32x4;
typedef __attribute__((ext_vector_type(4))) unsigned int u32x4;

__device__ inline unsigned short f2bf(float f) {
    unsigned u = __builtin_bit_cast(unsigned, f);
    u += 0x7fffu + ((u >> 16) & 1u);   // round-to-nearest-even
    return (unsigned short)(u >> 16);
}
__device__ inline float bf2f(unsigned short h) {
    unsigned u = ((unsigned)h) << 16;
    return __builtin_bit_cast(float, u);
}
__device__ inline unsigned cvtpk_bf16(float lo, float hi) {
    unsigned r;
    asm("v_cvt_pk_bf16_f32 %0, %1, %2" : "=v"(r) : "v"(lo), "v"(hi));
    return r;
}

// Parity-split DCT matrices: Ce[kk][n] = C[2kk][n], Co[kk][n] = C[2kk+1][n], n<256.
__global__ __launch_bounds__(256) void fill_dct_half(unsigned short* __restrict__ Ce,
                                                     unsigned short* __restrict__ Co) {
    int idx = blockIdx.x * 256 + threadIdx.x;     // 0..131071
    int par = idx >> 16;
    int kk = (idx >> 8) & 255;
    int n = idx & 255;
    int k = 2 * kk + par;
    int m = ((2 * n + 1) * k) & 2047;
    float ang = (float)m * 3.0679615757712823e-3f;   // * pi/1024
    float s = (k == 0) ? 0.04419417382415922f : 0.0625f;
    unsigned short v = f2bf(s * cosf(ang));
    if (par) Co[kk * 256 + n] = v; else Ce[kk * 256 + n] = v;
}

#define GLB(p) ((const __attribute__((address_space(1))) unsigned int*)(const void*)(p))
#define LDS(p) ((__attribute__((address_space(3))) unsigned int*)(p))

// R14: direct-to-register folded operand; LDS staging only for Ce/Co.
//  - R13 spilled (acc64 geometry needs >128 regs at 2 blk/CU) -> reverted to
//    R12 geometry (128x128, 8 waves 4x2, acc[2][4]).
//  - The folded operand (X in p1, T' in p2) no longer round-trips through
//    LDS: each wave loads its own A/B fragment rows direct from global
//    (32B fwd + 32B mirror per lane, contiguous) and folds in-register.
//    Removes cw VALU-staging chain, ds_write, and 2/6 -> 0 of the staged-
//    side LDS reads; wc/wr duplication of rows is L1-resident.
//  - Ce/Co keeps gload_lds 3-buf staging (24KB). 1 barrier/step guards only
//    that. No manual vmcnt in-loop: stage(kt+2) is issued BEFORE loadRaw
//    (kt+1), so the compiler's counted wait on raw regs at fold(kt)
//    retires stage(kt+1) ahead of its barrier (FIFO order). Prologue uses
//    one conservative vmcnt(0).
//  - Regs: ~103/thread both passes < 128 cap at (512,4) -> no spill, 2
//    blocks/CU (LDS 33KB p1 / 24KB p2 would allow 4; regs limit).
// PASS 1: T'[k][r] = sum_n (x[r][n] +- x[r][511-n]) * Ce/Co[k'][n]
//         bx<2 even k (+), bx>=2 odd k (-). A=X direct+fold; B=Ce/Co LDS.
// PASS 2: Out[q][k] = sum_r Ce/Co[q'][r] * (T'[k][r] +- T'[k][511-r])
//         by<2 even q (+), by>=2 odd q (-). A=Ce/Co LDS; B=T' direct+fold.
template <int PASS>
__global__ __launch_bounds__(512, 4) void gemm_dct(const void* __restrict__ Ap,
                                                   const unsigned short* __restrict__ Ce,
                                                   const unsigned short* __restrict__ Cop,
                                                   void* __restrict__ Outp,
                                                   size_t strideIn, size_t strideOut) {
    const int nwg = (int)gridDim.x;
    const int cpx = nwg >> 3;
    const int bid = (int)blockIdx.x;
    const int nid = (bid & 7) * cpx + (bid >> 3);   // bijective XCD swizzle (nwg%8==0)
    const int bx = nid & 3;
    const int by = (nid >> 2) & 3;
    const int bz = nid >> 4;

    // Gs: 3 x 4096 shorts (128x32 C-tile per step). p1 epilogue 128x132
    // shorts unions over it (16896 shorts total).
    __shared__ unsigned short sm[PASS == 1 ? 16896 : 12288];
    unsigned short* const Gs = sm;

    const int t = threadIdx.x;
    const int lane = t & 63;
    const int wave = t >> 6;                 // 0..7
    const int wr = wave >> 1;                // 0..3: folded-side 32-row strip
    const int wc = wave & 1;                 // 0..1: C-side 64-row strip
    const int lr = lane & 15;
    const int oct = lane >> 4;               // 0..3: K-octet
    const int kgx = (oct * 8) ^ (((lr >> 1) & 3) << 3);

    // gload staging (Ce/Co): 128 rows x 32 cols per step, pre-swizzled source
    const int srow = t >> 2;
    const int sslot = t & 3;
    const int scol = (sslot ^ ((srow >> 1) & 3)) * 8;

    const float* Xf = nullptr;
    const unsigned short* Tp = nullptr;
    const unsigned short* Gmat;
    int grow0, sgn, row0, col0;
    if constexpr (PASS == 1) {
        Xf = (const float*)Ap + (size_t)bz * strideIn;
        row0 = by * 128;
        col0 = bx * 128;
        Gmat = (bx < 2) ? Ce : Cop; grow0 = (bx & 1) * 128; sgn = (bx >= 2);
    } else {
        Tp = (const unsigned short*)Ap + (size_t)bz * strideIn;
        col0 = bx * 128;
        row0 = 0;
        Gmat = (by < 2) ? Ce : Cop; grow0 = (by & 1) * 128; sgn = (by >= 2);
    }
    const float sgnf = sgn ? -1.0f : 1.0f;

    f32x4 acc[2][4] = {};

    // raw folded-operand tiles, depth-1 (consumed next step)
    f32x4 xf[2][2], xm[2][2];    // pass 1: 2 frags x (8 fwd + 8 mir) fp32
    bf16x8 tf[4], tm[4];         // pass 2: 4 frags x (8 fwd + 8 mir) bf16

    auto stageG = [&](int buf, int k0) {
        __builtin_amdgcn_global_load_lds(GLB(Gmat + (size_t)(grow0 + srow) * 256 + k0 + scol),
                                         LDS(&Gs[buf * 4096 + srow * 32 + sslot * 8]), 16, 0, 0);
    };
    auto loadRaw = [&](int k0) {
        if constexpr (PASS == 1) {
#pragma unroll
            for (int mi = 0; mi < 2; ++mi) {
                const float* rp = Xf + (size_t)(row0 + wr * 32 + mi * 16 + lr) * NN;
                const float* fp = rp + k0 + oct * 8;
                const float* mp = rp + (504 - k0 - oct * 8);
                xf[mi][0] = *reinterpret_cast<const f32x4*>(fp);
                xf[mi][1] = *reinterpret_cast<const f32x4*>(fp + 4);
                xm[mi][0] = *reinterpret_cast<const f32x4*>(mp);
                xm[mi][1] = *reinterpret_cast<const f32x4*>(mp + 4);
            }
        } else {
#pragma unroll
            for (int ni = 0; ni < 4; ++ni) {
                const unsigned short* rp = Tp + (size_t)(col0 + wc * 64 + ni * 16 + lr) * NN;
                tf[ni] = *reinterpret_cast<const bf16x8*>(rp + k0 + oct * 8);
                tm[ni] = *reinterpret_cast<const bf16x8*>(rp + (504 - k0 - oct * 8));
            }
        }
    };

    auto step = [&](int kt, bool doStage, bool doLoad) {
        const int gofs = (kt % 3) * 4096;
        if (doStage) stageG((kt + 2) % 3, (kt + 2) * 32);
        asm volatile("" ::: "memory");       // pin FIFO: stage(kt+2) before loadRaw(kt+1)

        // fold current raw tile into MFMA fragments (compiler-counted vmcnt wait
        // on the raw regs; retires stage(kt+1) as an older FIFO entry)
        bf16x8 fr[PASS == 1 ? 2 : 4];
        if constexpr (PASS == 1) {
#pragma unroll
            for (int mi = 0; mi < 2; ++mi) {
                float f[8];
#pragma unroll
                for (int j = 0; j < 8; ++j) {
                    const int r = 7 - j;
                    float w = xf[mi][j >> 2][j & 3];
                    float m = xm[mi][r >> 2][r & 3];
                    f[j] = fmaf(sgnf, m, w);
                }
                u32x4 pk = {cvtpk_bf16(f[0], f[1]), cvtpk_bf16(f[2], f[3]),
                            cvtpk_bf16(f[4], f[5]), cvtpk_bf16(f[6], f[7])};
                fr[mi] = __builtin_bit_cast(bf16x8, pk);
            }
        } else {
#pragma unroll
            for (int ni = 0; ni < 4; ++ni) {
                float f[8];
#pragma unroll
                for (int j = 0; j < 8; ++j) {
                    float w = bf2f((unsigned short)tf[ni][j]);
                    float m = bf2f((unsigned short)tm[ni][7 - j]);
                    f[j] = fmaf(sgnf, m, w);
                }
                u32x4 pk = {cvtpk_bf16(f[0], f[1]), cvtpk_bf16(f[2], f[3]),
                            cvtpk_bf16(f[4], f[5]), cvtpk_bf16(f[6], f[7])};
                fr[ni] = __builtin_bit_cast(bf16x8, pk);
            }
        }

        if (doLoad) loadRaw((kt + 1) * 32);  // WAR on raw regs serializes after fold

        // C-side fragments from LDS + MFMA
        __builtin_amdgcn_s_setprio(1);
        if constexpr (PASS == 1) {
            bf16x8 b[4];
#pragma unroll
            for (int ni = 0; ni < 4; ++ni)
                b[ni] = *reinterpret_cast<const bf16x8*>(
                    &Gs[gofs + (wc * 64 + ni * 16 + lr) * 32 + kgx]);
#pragma unroll
            for (int mi = 0; mi < 2; ++mi)
#pragma unroll
                for (int ni = 0; ni < 4; ++ni)
                    acc[mi][ni] = __builtin_amdgcn_mfma_f32_16x16x32_bf16(fr[mi], b[ni],
                                                                          acc[mi][ni], 0, 0, 0);
        } else {
            bf16x8 a[2];
#pragma unroll
            for (int mi = 0; mi < 2; ++mi)
                a[mi] = *reinterpret_cast<const bf16x8*>(
                    &Gs[gofs + (wr * 32 + mi * 16 + lr) * 32 + kgx]);
#pragma unroll
            for (int mi = 0; mi < 2; ++mi)
#pragma unroll
                for (int ni = 0; ni < 4; ++ni)
                    acc[mi][ni] = __builtin_amdgcn_mfma_f32_16x16x32_bf16(a[mi], fr[ni],
                                                                          acc[mi][ni], 0, 0, 0);
        }
        __builtin_amdgcn_s_setprio(0);
    };

    // ---- prologue: C-steps 0,1 staged; raw step 0 in flight; hard drain ----
    stageG(0, 0);
    stageG(1, 32);
    asm volatile("" ::: "memory");
    loadRaw(0);
    asm volatile("s_waitcnt vmcnt(0)" ::: "memory");
    __builtin_amdgcn_s_barrier();

    // ---- 8 K-steps, fully unrolled; 1 barrier per step ----
#pragma unroll
    for (int kt = 0; kt < 8; ++kt) {
        step(kt, kt + 2 <= 7, kt + 1 <= 7);
        if (kt < 7) __builtin_amdgcn_s_barrier();
    }

    // ---- epilogue. C/D frag: row = (lane>>4)*4 + reg, col = lane&15 ----
    if constexpr (PASS == 1) {
        // LDS-staged transposed store (unions with Gs; barrier first: other
        // waves may still be reading staging in step 7).
        unsigned short* T = (unsigned short*)Outp + (size_t)bz * strideOut;
        __builtin_amdgcn_s_barrier();
#pragma unroll
        for (int mi = 0; mi < 2; ++mi)
#pragma unroll
            for (int ni = 0; ni < 4; ++ni) {
                int gr = wr * 32 + mi * 16 + (lane >> 4) * 4;   // local r (0..127)
                int gc = wc * 64 + ni * 16 + lr;                // local k' (0..127)
                ushort4 v;
                v.x = f2bf(acc[mi][ni][0]);
                v.y = f2bf(acc[mi][ni][1]);
                v.z = f2bf(acc[mi][ni][2]);
                v.w = f2bf(acc[mi][ni][3]);
                *reinterpret_cast<ushort4*>(&sm[gc * 132 + gr]) = v;
            }
        asm volatile("s_waitcnt lgkmcnt(0)" ::: "memory");
        __builtin_amdgcn_s_barrier();
#pragma unroll
        for (int it = 0; it < 4; ++it) {
            int gcr = it * 32 + (t >> 4);                       // local k' (0..127)
            int physRow = (bx & 1) * 256 + 2 * gcr + (bx >> 1); // natural k
            int cb = (t & 15) * 8;
            u32x4 d = *reinterpret_cast<const u32x4*>(&sm[gcr * 132 + cb]);
            *reinterpret_cast<u32x4*>(&T[(size_t)physRow * NN + row0 + cb]) = d;
        }
    } else {
        float* O = (float*)Outp + (size_t)bz * strideOut;
#pragma unroll
        for (int mi = 0; mi < 2; ++mi)
#pragma unroll
            for (int ni = 0; ni < 4; ++ni) {
                int gc = col0 + wc * 64 + ni * 16 + lr;         // natural k col
#pragma unroll
                for (int rr = 0; rr < 4; ++rr) {
                    int grl = wr * 32 + mi * 16 + (lane >> 4) * 4 + rr;  // local q'
                    int ih = (by & 1) * 128 + grl;
                    int q = 2 * ih + (by >> 1);                 // natural q row
                    O[(size_t)q * NN + gc] = acc[mi][ni][rr];
                }
            }
    }
}

extern "C" void kernel_launch(void* const* d_in, const int* in_sizes, int n_in,
                              void* d_out, int out_size, void* d_ws, size_t ws_size,
                              hipStream_t stream) {
    const float* x = (const float*)d_in[0];
    float* out = (float*)d_out;

    const int imgs = in_sizes[0] / (NN * NN);            // 96
    const size_t imgElems = (size_t)NN * NN;             // 262144
    const size_t imgB16 = imgElems * 2;                  // 512 KB

    unsigned short* Ce = (unsigned short*)d_ws;          // 128 KB
    unsigned short* Co = Ce + 65536;                     // 128 KB
    unsigned short* Tb = Co + 65536;                     // T' buffers

    long long budget = (long long)ws_size - 262144;
    int maxchunk = (int)(budget / (long long)imgB16);
    if (maxchunk < 1) maxchunk = 1;
    if (maxchunk > imgs) maxchunk = imgs;

    hipLaunchKernelGGL(fill_dct_half, dim3(512), dim3(256), 0, stream, Ce, Co);

    for (int i0 = 0; i0 < imgs; i0 += maxchunk) {
        int c = imgs - i0 < maxchunk ? imgs - i0 : maxchunk;
        hipLaunchKernelGGL((gemm_dct<1>), dim3(16 * c), dim3(512), 0, stream,
                           x + (size_t)i0 * imgElems, Ce, Co, Tb, imgElems, imgElems);
        hipLaunchKernelGGL((gemm_dct<2>), dim3(16 * c), dim3(512), 0, stream,
                           Tb, Ce, Co, out + (size_t)i0 * imgElems, imgElems, imgElems);
    }
}

// Round 8
// 69.102 us; speedup vs baseline: 2.9122x; 2.9122x over previous
//
#include <hip/hip_runtime.h>
#include <math.h>

#define NN 512

typedef __attribute__((ext_vector_type(8))) short bf16x8;
typedef __attribute__((ext_vector_type(4))) float f32x4;
typedef __attribute__((ext_vector_type(4))) unsigned int u32x4;

__device__ inline unsigned short f2bf(float f) {
    unsigned u = __builtin_bit_cast(unsigned, f);
    u += 0x7fffu + ((u >> 16) & 1u);   // round-to-nearest-even
    return (unsigned short)(u >> 16);
}
__device__ inline float bf2f(unsigned short h) {
    unsigned u = ((unsigned)h) << 16;
    return __builtin_bit_cast(float, u);
}
__device__ inline unsigned cvtpk_bf16(float lo, float hi) {
    unsigned r;
    asm("v_cvt_pk_bf16_f32 %0, %1, %2" : "=v"(r) : "v"(lo), "v"(hi));
    return r;
}

// Parity-split DCT matrices: Ce[kk][n] = C[2kk][n], Co[kk][n] = C[2kk+1][n], n<256.
__global__ __launch_bounds__(256) void fill_dct_half(unsigned short* __restrict__ Ce,
                                                     unsigned short* __restrict__ Co) {
    int idx = blockIdx.x * 256 + threadIdx.x;     // 0..131071
    int par = idx >> 16;
    int kk = (idx >> 8) & 255;
    int n = idx & 255;
    int k = 2 * kk + par;
    int m = ((2 * n + 1) * k) & 2047;
    float ang = (float)m * 3.0679615757712823e-3f;   // * pi/1024
    float s = (k == 0) ? 0.04419417382415922f : 0.0625f;
    unsigned short v = f2bf(s * cosf(ang));
    if (par) Co[kk * 256 + n] = v; else Ce[kk * 256 + n] = v;
}

#define GLB(p) ((const __attribute__((address_space(1))) unsigned int*)(const void*)(p))
#define LDS(p) ((__attribute__((address_space(3))) unsigned int*)(p))

// R15: R12 with BK=64 (4 K-steps) -- halve the barrier-convoy count.
//  - R14 (direct-to-reg operand) regressed 1.6x with CLEAN traffic: the
//    scattered per-wave gathers serialized RTT per step; LDS staging was
//    providing coalescing+buffering. Reverted to R12 base.
//  - Each 64-col step buffer = TWO R12-style 32-col sub-tiles (identical
//    swizzles -> zero-conflict layout preserved by construction).
//  - 4 steps: 2x MFMA per barrier interval, half the barriers, half the
//    per-step drain points. No manual vmcnt needed: cw(kt+1) dep-waits on
//    1-step-old raws, FIFO-drains the 1-step-old stage with it; this
//    step's stage/lr (issued after that wait point) ride through the
//    barrier. Only lgkmcnt(0)+s_barrier per step.
//  - LDS exactly 80KB/block (Gs 3x16KB + Rs 2x16KB) -> 2 blocks/CU.
//    Regs: p1 ~108, p2 ~84 under (512,4) cap 128 -> no spill expected.
//    Spill gate: FETCH/WRITE counters.
// PASS 1: T'[k][r] = sum_{n<256} (x[r][n] +- x[r][511-n]) * Ce/Co[k'][n]
//         bx<2 even k (+), bx>=2 odd k (-). B=Ce/Co gload_lds; A=X reg-staged.
// PASS 2: Out[q][k] = sum_{r<256} Ce/Co[q'][r] * (T'[k][r] +- T'[k][511-r])
//         by<2 even q (+), by>=2 odd q (-). A=Ce/Co gload_lds; B=T' reg-staged.
template <int PASS>
__global__ __launch_bounds__(512, 4) void gemm_dct(const void* __restrict__ Ap,
                                                   const unsigned short* __restrict__ Ce,
                                                   const unsigned short* __restrict__ Cop,
                                                   void* __restrict__ Outp,
                                                   size_t strideIn, size_t strideOut) {
    const int nwg = (int)gridDim.x;
    const int cpx = nwg >> 3;
    const int bid = (int)blockIdx.x;
    const int nid = (bid & 7) * cpx + (bid >> 3);   // bijective XCD swizzle (nwg%8==0)
    const int bx = nid & 3;
    const int by = (nid >> 2) & 3;
    const int bz = nid >> 4;

    // 81920 B: reg side 2 x 8192 shorts, gload side 3 x 8192 shorts.
    // p1 epilogue (128x132 = 16896 shorts) unions over the front.
    __shared__ unsigned short sm[40960];
    unsigned short* const Rs = (PASS == 1) ? sm : sm + 24576;   // reg-staged, 2 bufs
    unsigned short* const Gs = (PASS == 1) ? sm + 16384 : sm;   // gload, 3 bufs

    const int t = threadIdx.x;
    const int lane = t & 63;
    const int wave = t >> 6;                 // 0..7
    const int wr = wave >> 2;                // 0..1: A-side 64-row strip
    const int wc = wave & 3;                 // 0..3: B-side 32-row strip
    const int lr = lane & 15;
    const int kgx = ((lane >> 4) * 8) ^ (((lr >> 1) & 3) << 3);

    // gload staging: per step 2 halves of 128x32; R12 mapping per half.
    const int srow = t >> 2;                 // 0..127
    const int sslot = t & 3;
    const int scol = (sslot ^ ((srow >> 1) & 3)) * 8;

    // reg staging: per half, thread -> (row t>>2, 8-col slot t&3)
    const int frow = t >> 2;
    const int fq = t & 3;
    const int fslot = (fq ^ ((frow >> 1) & 3)) * 8;

    const float* Xf = nullptr;
    const unsigned short* Tp = nullptr;
    const unsigned short* Gmat;
    int grow0, sgn, row0, col0;
    if constexpr (PASS == 1) {
        Xf = (const float*)Ap + (size_t)bz * strideIn;
        row0 = by * 128;
        col0 = bx * 128;
        Gmat = (bx < 2) ? Ce : Cop; grow0 = (bx & 1) * 128; sgn = (bx >= 2);
    } else {
        Tp = (const unsigned short*)Ap + (size_t)bz * strideIn;
        col0 = bx * 128;
        row0 = 0;
        Gmat = (by < 2) ? Ce : Cop; grow0 = (by & 1) * 128; sgn = (by >= 2);
    }
    const float sgnf = sgn ? -1.0f : 1.0f;

    f32x4 acc[4][2] = {};

    // raw folded-operand regs for one 64-col step (fwd + mirror), per half h
    f32x4 rf[2][2], rm[2][2];    // pass 1 (fp32): [h][2 x f32x4]
    bf16x8 gf[2], gm[2];         // pass 2 (bf16): [h]

    auto stageG = [&](int buf, int k0) {
#pragma unroll
        for (int h = 0; h < 2; ++h)
            __builtin_amdgcn_global_load_lds(
                GLB(Gmat + (size_t)(grow0 + srow) * 256 + k0 + h * 32 + scol),
                LDS(&Gs[buf * 8192 + h * 4096 + srow * 32 + sslot * 8]), 16, 0, 0);
    };
    auto doLR = [&](int k0) {
        if constexpr (PASS == 1) {
#pragma unroll
            for (int h = 0; h < 2; ++h) {
                const float* bfp = Xf + (size_t)(row0 + frow) * NN + k0 + h * 32 + fq * 8;
                const float* bmp = Xf + (size_t)(row0 + frow) * NN + (504 - k0 - h * 32 - fq * 8);
                rf[h][0] = *reinterpret_cast<const f32x4*>(bfp);
                rf[h][1] = *reinterpret_cast<const f32x4*>(bfp + 4);
                rm[h][0] = *reinterpret_cast<const f32x4*>(bmp);
                rm[h][1] = *reinterpret_cast<const f32x4*>(bmp + 4);
            }
        } else {
#pragma unroll
            for (int h = 0; h < 2; ++h) {
                const unsigned short* bfp = Tp + (size_t)(col0 + frow) * NN + k0 + h * 32 + fq * 8;
                const unsigned short* bmp = Tp + (size_t)(col0 + frow) * NN + (504 - k0 - h * 32 - fq * 8);
                gf[h] = *reinterpret_cast<const bf16x8*>(bfp);
                gm[h] = *reinterpret_cast<const bf16x8*>(bmp);
            }
        }
    };
    auto doCW = [&](int s) {
        const int buf = s & 1;
#pragma unroll
        for (int h = 0; h < 2; ++h) {
            unsigned p[4];
            if constexpr (PASS == 1) {
#pragma unroll
                for (int q = 0; q < 4; ++q) {
                    const int j0 = 2 * q, j1 = 2 * q + 1;
                    const int r0 = 7 - j0, r1 = 7 - j1;
                    float s0 = fmaf(sgnf, rm[h][r0 >> 2][r0 & 3], rf[h][j0 >> 2][j0 & 3]);
                    float s1 = fmaf(sgnf, rm[h][r1 >> 2][r1 & 3], rf[h][j1 >> 2][j1 & 3]);
                    p[q] = cvtpk_bf16(s0, s1);
                }
            } else {
#pragma unroll
                for (int q = 0; q < 4; ++q) {
                    const int j0 = 2 * q, j1 = 2 * q + 1;
                    float a0 = bf2f((unsigned short)gf[h][j0]);
                    float a1 = bf2f((unsigned short)gf[h][j1]);
                    float b0 = bf2f((unsigned short)gm[h][7 - j0]);
                    float b1 = bf2f((unsigned short)gm[h][7 - j1]);
                    p[q] = cvtpk_bf16(fmaf(sgnf, b0, a0), fmaf(sgnf, b1, a1));
                }
            }
            u32x4 w = {p[0], p[1], p[2], p[3]};
            *reinterpret_cast<u32x4*>(&Rs[buf * 8192 + h * 4096 + frow * 32 + fslot]) = w;
        }
    };
    auto compute = [&](int kt) {
        const int rofs = (kt & 1) * 8192;
        const int gofs = (kt % 3) * 8192;
        const unsigned short* const Aside = (PASS == 1) ? Rs : Gs;
        const unsigned short* const Bside = (PASS == 1) ? Gs : Rs;
        const int aofs = (PASS == 1) ? rofs : gofs;
        const int bofs = (PASS == 1) ? gofs : rofs;
#pragma unroll
        for (int ks = 0; ks < 2; ++ks) {
            const int ho = ks * 4096;
            bf16x8 a[4], b[2];
#pragma unroll
            for (int mi = 0; mi < 4; ++mi)
                a[mi] = *reinterpret_cast<const bf16x8*>(
                    &Aside[aofs + ho + (wr * 64 + mi * 16 + lr) * 32 + kgx]);
#pragma unroll
            for (int ni = 0; ni < 2; ++ni)
                b[ni] = *reinterpret_cast<const bf16x8*>(
                    &Bside[bofs + ho + (wc * 32 + ni * 16 + lr) * 32 + kgx]);
            __builtin_amdgcn_s_setprio(1);
#pragma unroll
            for (int mi = 0; mi < 4; ++mi)
#pragma unroll
                for (int ni = 0; ni < 2; ++ni)
                    acc[mi][ni] = __builtin_amdgcn_mfma_f32_16x16x32_bf16(a[mi], b[ni],
                                                                          acc[mi][ni], 0, 0, 0);
            __builtin_amdgcn_s_setprio(0);
        }
    };

    // ---- prologue: steps 0,1 staged; raw(0) folded+written; raw(1) in flight ----
    stageG(0, 0);
    stageG(1, 64);
    asm volatile("" ::: "memory");      // pin: stages before raw loads in FIFO
    doLR(0);
    doCW(0);                            // dep-wait raw(0) -> FIFO-drains stage(0),(1)
    doLR(64);                           // raw for step 1 (WAR after cw)
    asm volatile("s_waitcnt lgkmcnt(0)" ::: "memory");
    __builtin_amdgcn_s_barrier();

    // ---- 4 K-steps of 64; 1 barrier per step; no manual vmcnt ----
#pragma unroll
    for (int kt = 0; kt < 4; ++kt) {
        if (kt + 2 <= 3) stageG((kt + 2) % 3, (kt + 2) * 64);
        asm volatile("" ::: "memory");  // pin: stage(kt+2) before lr(kt+2) in FIFO
        if (kt + 1 <= 3) doCW(kt + 1);  // dep-wait raw(kt+1) [1 step old] ->
                                        // FIFO-drains stage(kt+1); stage(kt+2) is
                                        // younger than the wait point -> stays in flight
        if (kt + 2 <= 3) doLR((kt + 2) * 64);   // WAR on raw regs after cw
        compute(kt);
        asm volatile("s_waitcnt lgkmcnt(0)" ::: "memory");
        if (kt < 3) __builtin_amdgcn_s_barrier();
    }

    // ---- epilogue. C/D frag: row = (lane>>4)*4 + reg, col = lane&15 ----
    if constexpr (PASS == 1) {
        // Transposed store with parity row permutation, staged via LDS
        // (unions over staging -> barrier first: other waves still reading).
        unsigned short* T = (unsigned short*)Outp + (size_t)bz * strideOut;
        __builtin_amdgcn_s_barrier();
#pragma unroll
        for (int mi = 0; mi < 4; ++mi)
#pragma unroll
            for (int ni = 0; ni < 2; ++ni) {
                int gr = wr * 64 + mi * 16 + (lane >> 4) * 4;   // local r (0..127)
                int gc = wc * 32 + ni * 16 + lr;                // local k' (0..127)
                ushort4 v;
                v.x = f2bf(acc[mi][ni][0]);
                v.y = f2bf(acc[mi][ni][1]);
                v.z = f2bf(acc[mi][ni][2]);
                v.w = f2bf(acc[mi][ni][3]);
                *reinterpret_cast<ushort4*>(&sm[gc * 132 + gr]) = v;
            }
        asm volatile("s_waitcnt lgkmcnt(0)" ::: "memory");
        __builtin_amdgcn_s_barrier();
#pragma unroll
        for (int it = 0; it < 4; ++it) {
            int gcr = wave * 16 + it * 4 + (lane >> 4);         // local k' (0..127)
            int physRow = (bx & 1) * 256 + 2 * gcr + (bx >> 1); // natural k
            int cb = lr * 8;
            u32x4 d = *reinterpret_cast<const u32x4*>(&sm[gcr * 132 + cb]);
            *reinterpret_cast<u32x4*>(&T[(size_t)physRow * NN + row0 + cb]) = d;
        }
    } else {
        float* O = (float*)Outp + (size_t)bz * strideOut;
#pragma unroll
        for (int mi = 0; mi < 4; ++mi)
#pragma unroll
            for (int ni = 0; ni < 2; ++ni) {
                int gc = col0 + wc * 32 + ni * 16 + lr;         // natural k col
#pragma unroll
                for (int rr = 0; rr < 4; ++rr) {
                    int grl = wr * 64 + mi * 16 + (lane >> 4) * 4 + rr;  // local q'
                    int ih = (by & 1) * 128 + grl;
                    int q = 2 * ih + (by >> 1);                 // natural q row
                    O[(size_t)q * NN + gc] = acc[mi][ni][rr];
                }
            }
    }
}

extern "C" void kernel_launch(void* const* d_in, const int* in_sizes, int n_in,
                              void* d_out, int out_size, void* d_ws, size_t ws_size,
                              hipStream_t stream) {
    const float* x = (const float*)d_in[0];
    float* out = (float*)d_out;

    const int imgs = in_sizes[0] / (NN * NN);            // 96
    const size_t imgElems = (size_t)NN * NN;             // 262144
    const size_t imgB16 = imgElems * 2;                  // 512 KB

    unsigned short* Ce = (unsigned short*)d_ws;          // 128 KB
    unsigned short* Co = Ce + 65536;                     // 128 KB
    unsigned short* Tb = Co + 65536;                     // T' buffers

    long long budget = (long long)ws_size - 262144;
    int maxchunk = (int)(budget / (long long)imgB16);
    if (maxchunk < 1) maxchunk = 1;
    if (maxchunk > imgs) maxchunk = imgs;

    hipLaunchKernelGGL(fill_dct_half, dim3(512), dim3(256), 0, stream, Ce, Co);

    for (int i0 = 0; i0 < imgs; i0 += maxchunk) {
        int c = imgs - i0 < maxchunk ? imgs - i0 : maxchunk;
        hipLaunchKernelGGL((gemm_dct<1>), dim3(16 * c), dim3(512), 0, stream,
                           x + (size_t)i0 * imgElems, Ce, Co, Tb, imgElems, imgElems);
        hipLaunchKernelGGL((gemm_dct<2>), dim3(16 * c), dim3(512), 0, stream,
                           Tb, Ce, Co, out + (size_t)i0 * imgElems, imgElems, imgElems);
    }
}